// Round 17
// baseline (437.762 us; speedup 1.0000x reference)
//
#include <hip/hip_runtime.h>
#include <hip/hip_bf16.h>
#include <hip/hip_fp16.h>
#include <math.h>

// ---------------------------------------------------------------------------
// 2-layer GCN (PyG GCNConv), fp32 compute, fp16 intermediates (L2-resident).
// Bucket sort (atomic-free) -> per-node CSR -> register-gather aggregation.
// Normalization factored: g = dinv*h; RAW edge weights; dinv[d] in epilogues.
// Measured: gemm1 = 38.5us (HBM floor, round 15). NBLK=1024 (+6us, round 16).
//
// ROUND 17 = ATTRIBUTION ROUND 2: agg16g2 and agg8lsm each launched 3x
// (idempotent). T = t_agg16 + t_agg8 = (dur - 271.5)/2. Streaming cost model
// leaves ~100us of the 271.5 unexplained; need to know if it's in the aggs
// before editing them. Baseline otherwise identical to round 16.
// edge_index arrives as int32 (harness converts integer inputs to int32).
// ---------------------------------------------------------------------------

#define NBLK 1024       // blocks in hist/bin passes (4/CU -> 16 waves/CU)
#define MAX_NBK 2048    // max buckets (n <= 131072); also pack limit n<2^20
#define CAP_SORTED 3072 // max bucket size for LDS-staged sort (avg 2048)

typedef _Float16 half8 __attribute__((ext_vector_type(8)));
typedef __fp16 fp16x2 __attribute__((ext_vector_type(2)));
typedef float f32x4 __attribute__((ext_vector_type(4)));

#define XPITCH 136      // LDS row pitch in fp16 (272B -> 2-way banks, free)

__device__ __forceinline__ float2 h2f(unsigned u) {
    __half2 h = *reinterpret_cast<__half2*>(&u);
    return __half22float2(h);
}

// Pass A: per-block histogram of dst>>6 over this block's edge chunk.
__global__ __launch_bounds__(256) void k_hist(const int* __restrict__ dst,
                                              int* __restrict__ bh,
                                              int NBK, int E, int chunk) {
    __shared__ int hist[MAX_NBK];
    int blk = blockIdx.x, tid = threadIdx.x;
    for (int b = tid; b < NBK; b += 256) hist[b] = 0;
    __syncthreads();
    int lo = blk * chunk, hi = min(lo + chunk, E);
    for (int e = lo + tid; e < hi; e += 256) atomicAdd(&hist[dst[e] >> 6], 1);
    __syncthreads();
    for (int b = tid; b < NBK; b += 256) bh[(size_t)blk * NBK + b] = hist[b];
}

// Pass B1: per-bucket exclusive scan over the NBLK block counts (in place);
// each thread owns 4 consecutive rows (NBLK = 4*256).
__global__ __launch_bounds__(256) void k_colscan(int* __restrict__ bh,
                                                 int* __restrict__ totals, int NBK) {
    __shared__ int s[256];
    int b = blockIdx.x, t = threadIdx.x;
    int v0 = bh[(size_t)(4 * t + 0) * NBK + b];
    int v1 = bh[(size_t)(4 * t + 1) * NBK + b];
    int v2 = bh[(size_t)(4 * t + 2) * NBK + b];
    int v3 = bh[(size_t)(4 * t + 3) * NBK + b];
    int lsum = v0 + v1 + v2 + v3;
    s[t] = lsum;
    __syncthreads();
    for (int off = 1; off < 256; off <<= 1) {
        int u = (t >= off) ? s[t - off] : 0;
        __syncthreads();
        s[t] += u;
        __syncthreads();
    }
    int pre = s[t] - lsum;  // exclusive prefix of this thread's 4-row group
    bh[(size_t)(4 * t + 0) * NBK + b] = pre;
    bh[(size_t)(4 * t + 1) * NBK + b] = pre + v0;
    bh[(size_t)(4 * t + 2) * NBK + b] = pre + v0 + v1;
    bh[(size_t)(4 * t + 3) * NBK + b] = pre + v0 + v1 + v2;
    if (t == 255) totals[b] = s[255];
}

// Pass B2: exclusive scan of bucket totals -> bucketStart[NBK+1].
__global__ __launch_bounds__(256) void k_scan_totals(const int* __restrict__ totals,
                                                     int* __restrict__ bs,
                                                     int NBK, int E) {
    __shared__ int s[256];
    int t = threadIdx.x;
    int chunk = (NBK + 255) >> 8;
    int lo = t * chunk, hi = min(lo + chunk, NBK);
    int acc = 0;
    for (int i = lo; i < hi; ++i) acc += totals[i];
    s[t] = acc;
    __syncthreads();
    for (int off = 1; off < 256; off <<= 1) {
        int u = (t >= off) ? s[t - off] : 0;
        __syncthreads();
        s[t] += u;
        __syncthreads();
    }
    int pre = (t == 0) ? 0 : s[t - 1];
    for (int i = lo; i < hi; ++i) { bs[i] = pre; pre += totals[i]; }
    if (t == 0) bs[NBK] = E;
}

// Pass C: scatter edges into bucket regions (exclusive slices -> LDS cursors,
// zero global atomics). Edge packed: src | dstlow<<20, raw weight.
__global__ __launch_bounds__(256) void k_bin(const int* __restrict__ src,
                                             const int* __restrict__ dst,
                                             const float* __restrict__ w,
                                             const int* __restrict__ bh,
                                             const int* __restrict__ bs,
                                             uint2* __restrict__ ebuf,
                                             int NBK, int E, int chunk) {
    __shared__ int cur[MAX_NBK];
    int blk = blockIdx.x, tid = threadIdx.x;
    for (int b = tid; b < NBK; b += 256)
        cur[b] = bs[b] + bh[(size_t)blk * NBK + b];
    __syncthreads();
    int lo = blk * chunk, hi = min(lo + chunk, E);
    for (int e = lo + tid; e < hi; e += 256) {
        int d = dst[e];
        int b = d >> 6;
        int pos = atomicAdd(&cur[b], 1);  // LDS atomic (few collisions)
        ebuf[pos] = make_uint2((unsigned)src[e] | ((unsigned)(d & 63) << 20),
                               __float_as_uint(w[e]));
    }
}

// Pass D: within-bucket counting sort by dl (LDS-staged, in place) -> full
// per-node CSR. Also computes deg -> dinv and node rowptr. Buckets larger
// than CAP_SORTED are left unsorted (agg kernels fall back for those).
__global__ __launch_bounds__(256) void k_sortdeg(uint2* __restrict__ ebuf,
                                                 const int* __restrict__ bs,
                                                 int* __restrict__ nrp,
                                                 float* __restrict__ dinv,
                                                 int n, int NBK, int E) {
    __shared__ uint2 stage[CAP_SORTED];
    __shared__ int cnt[64];
    __shared__ float dw[64];
    __shared__ int cur[64];
    int b = blockIdx.x, tid = threadIdx.x;
    if (tid < 64) { cnt[tid] = 0; dw[tid] = 1.0f; }  // self-loop weight 1
    __syncthreads();
    int e0 = bs[b], e1 = bs[b + 1];
    int m = e1 - e0;
    bool sorted = (m <= CAP_SORTED);
    if (sorted) {
        for (int i = tid; i < m; i += 256) {
            uint2 p = ebuf[e0 + i];
            stage[i] = p;
            int dl = p.x >> 20;
            atomicAdd(&cnt[dl], 1);
            atomicAdd(&dw[dl], __uint_as_float(p.y));
        }
    } else {
        for (int i = tid; i < m; i += 256) {
            uint2 p = ebuf[e0 + i];
            int dl = p.x >> 20;
            atomicAdd(&cnt[dl], 1);
            atomicAdd(&dw[dl], __uint_as_float(p.y));
        }
    }
    __syncthreads();
    if (tid < 64) {
        int v = cnt[tid], x = v;
#pragma unroll
        for (int off = 1; off < 64; off <<= 1) {
            int y = __shfl_up(x, off);
            if (tid >= off) x += y;
        }
        int pre = x - v;  // exclusive prefix within bucket
        cur[tid] = pre;
        int node = b * 64 + tid;
        if (node < n) {
            nrp[node] = e0 + pre;
            dinv[node] = rsqrtf(dw[tid]);
        }
    }
    if (b == NBK - 1 && tid == 0) nrp[n] = E;
    __syncthreads();
    if (sorted) {
        for (int i = tid; i < m; i += 256) {
            uint2 p = stage[i];
            int dl = p.x >> 20;
            int pos = atomicAdd(&cur[dl], 1);
            ebuf[e0 + pos] = p;
        }
    }
}

// W1 [512][16] fp32 -> W1h [16][512] fp16 (col-major for 16B B-frag loads).
__global__ __launch_bounds__(256) void k_prepW(const float* __restrict__ W1,
                                               _Float16* __restrict__ W1h) {
    int idx = blockIdx.x * 256 + threadIdx.x;
    if (idx < 512 * 16) {
        int k = idx >> 4, c = idx & 15;
        W1h[c * 512 + k] = (_Float16)W1[idx];
    }
}

// g1 = dinv * (x @ W1) via MFMA f32_16x16x32_f16, LDS-staged coalesced A.
// Measured round 15: ~38.5us (~HBM floor for 205MB x read) — do not touch.
__global__ __launch_bounds__(256) void k_gemm1(const float* __restrict__ x,
                                               const _Float16* __restrict__ W1h,
                                               const float* __restrict__ dinv,
                                               __half* __restrict__ g1, int n) {
    __shared__ _Float16 xlds[64 * XPITCH];
    int tid = threadIdx.x;
    int wave = tid >> 6, lane = tid & 63;
    int col = lane & 15;
    int kgrp = lane >> 4;
    const half8* wcol = (const half8*)(W1h + (size_t)col * 512);
    half8 bfrag[16];
#pragma unroll
    for (int t = 0; t < 16; ++t) bfrag[t] = wcol[t * 4 + kgrp];

    int rbase = blockIdx.x * 64;
    if (rbase >= n) return;
    int srow = tid >> 5;            // 0..7 (+8 per i)
    int sc4  = tid & 31;            // float4 col within 128-float chunk
    int rowl = wave * 16 + col;     // this lane's A row (local)
    f32x4 acc = {0.f, 0.f, 0.f, 0.f};
#pragma unroll
    for (int c = 0; c < 4; ++c) {   // K-chunk: floats [c*128, c*128+128)
#pragma unroll
        for (int i = 0; i < 8; ++i) {
            int row = srow + i * 8;
            int grow = min(rbase + row, n - 1);
            float4 v = *(const float4*)(x + (size_t)grow * 512 + c * 128 + sc4 * 4);
            union { fp16x2 h[2]; uint2 u; } pk;
            pk.h[0] = __builtin_amdgcn_cvt_pkrtz(v.x, v.y);
            pk.h[1] = __builtin_amdgcn_cvt_pkrtz(v.z, v.w);
            *(uint2*)(&xlds[row * XPITCH + sc4 * 4]) = pk.u;
        }
        __syncthreads();
#pragma unroll
        for (int s = 0; s < 4; ++s) {
            half8 a = *(const half8*)(&xlds[rowl * XPITCH + s * 32 + kgrp * 8]);
            acc = __builtin_amdgcn_mfma_f32_16x16x32_f16(a, bfrag[c * 4 + s], acc, 0, 0, 0);
        }
        __syncthreads();
    }
#pragma unroll
    for (int r = 0; r < 4; ++r) {
        int node = rbase + wave * 16 + kgrp * 4 + r;
        if (node < n) {
            float dv = dinv[node];
            g1[(size_t)node * 16 + col] = __float2half(acc[r] * dv);
        }
    }
}

// Layer-1 aggregation over g1 with RAW weights, 4 threads/node, 4 ch each,
// register accumulation (NO atomics). Epilogue: pre = dinv[d]*acc; fused
// gemm2: g2 = dinv[d] * (relu(pre + b1) @ W2).
__global__ __launch_bounds__(256) void k_agg16g2(const int* __restrict__ nrp,
                                                 const uint2* __restrict__ ebuf,
                                                 const int* __restrict__ bs,
                                                 const float* __restrict__ dinv,
                                                 const __half* __restrict__ g1,
                                                 const float* __restrict__ W2,
                                                 const float* __restrict__ b1,
                                                 __half* __restrict__ g2, int n) {
    __shared__ float acc[64 * 17];
    __shared__ float w2s[16 * 8];
    __shared__ float b1s[16];
    int b = blockIdx.x, tid = threadIdx.x;
    int nodeBase = b * 64;
    if (tid < 128) w2s[tid] = W2[tid];
    if (tid < 16) b1s[tid] = b1[tid];
    int e0 = bs[b], e1 = bs[b + 1];
    int m = e1 - e0;
    if (m <= CAP_SORTED) {
        int l = tid >> 2, q = tid & 3;  // node-local index, channel quad
        int node = nodeBase + l;
        if (node < n) {
            uint2 hv = *(const uint2*)(g1 + (size_t)node * 16 + q * 4);
            float2 f0 = h2f(hv.x), f1 = h2f(hv.y);
            float a0 = f0.x, a1 = f0.y, a2 = f1.x, a3 = f1.y;  // self: g1[d]
            int e = nrp[node], eE = nrp[node + 1];
            for (; e < eE; ++e) {
                uint2 p = ebuf[e];
                float wE = __uint_as_float(p.y);  // RAW weight
                unsigned s = p.x & 0xFFFFF;
                uint2 g = *(const uint2*)(g1 + (size_t)s * 16 + q * 4);
                float2 g0 = h2f(g.x), g1v = h2f(g.y);
                a0 = fmaf(wE, g0.x, a0);
                a1 = fmaf(wE, g0.y, a1);
                a2 = fmaf(wE, g1v.x, a2);
                a3 = fmaf(wE, g1v.y, a3);
            }
            float* ar = &acc[l * 17 + q * 4];
            ar[0] = a0; ar[1] = a1; ar[2] = a2; ar[3] = a3;
        }
    } else {
        for (int o = tid; o < 64 * 16; o += 256) {
            int l = o >> 4, c = o & 15;
            int node = nodeBase + l;
            float v = 0.f;
            if (node < n) v = __half2float(g1[(size_t)node * 16 + c]);
            acc[l * 17 + c] = v;
        }
        __syncthreads();
        for (int e = e0 + tid; e < e1; e += 256) {
            uint2 p = ebuf[e];
            int s = p.x & 0xFFFFF;
            int dl = p.x >> 20;
            float wE = __uint_as_float(p.y);
            const uint4* hr = (const uint4*)(g1 + (size_t)s * 16);
            uint4 q0 = hr[0], q1 = hr[1];
            float* ar = &acc[dl * 17];
            float2 f;
            f = h2f(q0.x); atomicAdd(ar + 0,  wE * f.x); atomicAdd(ar + 1,  wE * f.y);
            f = h2f(q0.y); atomicAdd(ar + 2,  wE * f.x); atomicAdd(ar + 3,  wE * f.y);
            f = h2f(q0.z); atomicAdd(ar + 4,  wE * f.x); atomicAdd(ar + 5,  wE * f.y);
            f = h2f(q0.w); atomicAdd(ar + 6,  wE * f.x); atomicAdd(ar + 7,  wE * f.y);
            f = h2f(q1.x); atomicAdd(ar + 8,  wE * f.x); atomicAdd(ar + 9,  wE * f.y);
            f = h2f(q1.y); atomicAdd(ar + 10, wE * f.x); atomicAdd(ar + 11, wE * f.y);
            f = h2f(q1.z); atomicAdd(ar + 12, wE * f.x); atomicAdd(ar + 13, wE * f.y);
            f = h2f(q1.w); atomicAdd(ar + 14, wE * f.x); atomicAdd(ar + 15, wE * f.y);
        }
    }
    __syncthreads();
    // fused gemm2: g2[64x8] = dinv * (relu(dinv*acc + b1) @ W2)
    for (int o = tid; o < 64 * 8; o += 256) {
        int l = o >> 3, cc = o & 7;
        int node = nodeBase + l;
        if (node >= n) continue;
        float dv = dinv[node];
        float s = 0.f;
#pragma unroll
        for (int k = 0; k < 16; ++k) {
            float v = fmaxf(fmaf(dv, acc[l * 17 + k], b1s[k]), 0.f);
            s = fmaf(v, w2s[k * 8 + cc], s);
        }
        g2[(size_t)node * 8 + cc] = __float2half(s * dv);
    }
}

// Layer-2 aggregation over g2 with RAW weights, 4 threads/node, 2 ch each.
// Epilogue: v = dinv[d]*acc + b2 -> log_softmax.
__global__ __launch_bounds__(256) void k_agg8lsm(const int* __restrict__ nrp,
                                                 const uint2* __restrict__ ebuf,
                                                 const int* __restrict__ bs,
                                                 const float* __restrict__ dinv,
                                                 const __half* __restrict__ g2,
                                                 const float* __restrict__ b2,
                                                 float* __restrict__ out, int n) {
    __shared__ float acc[64 * 9];
    __shared__ float b2s[8];
    int b = blockIdx.x, tid = threadIdx.x;
    int nodeBase = b * 64;
    if (tid < 8) b2s[tid] = b2[tid];
    int e0 = bs[b], e1 = bs[b + 1];
    int m = e1 - e0;
    if (m <= CAP_SORTED) {
        int l = tid >> 2, q = tid & 3;  // node-local index, channel pair
        int node = nodeBase + l;
        if (node < n) {
            unsigned hv = *(const unsigned*)(g2 + (size_t)node * 8 + q * 2);
            float2 f = h2f(hv);
            float a0 = f.x, a1 = f.y;   // self: g2[d]
            int e = nrp[node], eE = nrp[node + 1];
            for (; e < eE; ++e) {
                uint2 p = ebuf[e];
                float wE = __uint_as_float(p.y);
                unsigned s = p.x & 0xFFFFF;
                unsigned g = *(const unsigned*)(g2 + (size_t)s * 8 + q * 2);
                float2 gf = h2f(g);
                a0 = fmaf(wE, gf.x, a0);
                a1 = fmaf(wE, gf.y, a1);
            }
            acc[l * 9 + q * 2] = a0;
            acc[l * 9 + q * 2 + 1] = a1;
        }
    } else {
        for (int o = tid; o < 64 * 8; o += 256) {
            int l = o >> 3, c = o & 7;
            int node = nodeBase + l;
            float v = 0.f;
            if (node < n) v = __half2float(g2[(size_t)node * 8 + c]);
            acc[l * 9 + c] = v;
        }
        __syncthreads();
        for (int e = e0 + tid; e < e1; e += 256) {
            uint2 p = ebuf[e];
            int s = p.x & 0xFFFFF;
            int dl = p.x >> 20;
            float wE = __uint_as_float(p.y);
            const uint4* hr = (const uint4*)(g2 + (size_t)s * 8);
            uint4 q0 = hr[0];
            float* ar = &acc[dl * 9];
            float2 f;
            f = h2f(q0.x); atomicAdd(ar + 0, wE * f.x); atomicAdd(ar + 1, wE * f.y);
            f = h2f(q0.y); atomicAdd(ar + 2, wE * f.x); atomicAdd(ar + 3, wE * f.y);
            f = h2f(q0.z); atomicAdd(ar + 4, wE * f.x); atomicAdd(ar + 5, wE * f.y);
            f = h2f(q0.w); atomicAdd(ar + 6, wE * f.x); atomicAdd(ar + 7, wE * f.y);
        }
    }
    __syncthreads();
    if (tid < 64) {
        int node = nodeBase + tid;
        if (node < n) {
            float dv = dinv[node];
            float v[8];
#pragma unroll
            for (int cc = 0; cc < 8; ++cc) v[cc] = fmaf(dv, acc[tid * 9 + cc], b2s[cc]);
            float mx = v[0];
#pragma unroll
            for (int cc = 1; cc < 8; ++cc) mx = fmaxf(mx, v[cc]);
            float sum = 0.f;
#pragma unroll
            for (int cc = 0; cc < 8; ++cc) sum += expf(v[cc] - mx);
            float lg = mx + logf(sum);
#pragma unroll
            for (int cc = 0; cc < 8; ++cc) out[(size_t)node * 8 + cc] = v[cc] - lg;
        }
    }
}

// -------------------- fallback (atomic scatter, proven correct) ------------
__global__ void k_init_deg(float* __restrict__ deg, int n) {
    int i = blockIdx.x * blockDim.x + threadIdx.x;
    if (i < n) deg[i] = 1.0f;
}
__global__ void k_deg_scatter(const int* __restrict__ dst, const float* __restrict__ w,
                              float* __restrict__ deg, int E) {
    int e = blockIdx.x * blockDim.x + threadIdx.x;
    if (e < E) atomicAdd(&deg[dst[e]], w[e]);
}
__global__ void k_rsqrt_inplace(float* __restrict__ deg, int n) {
    int i = blockIdx.x * blockDim.x + threadIdx.x;
    if (i < n) { float d = deg[i]; deg[i] = d > 0.0f ? rsqrtf(d) : 0.0f; }
}
__global__ __launch_bounds__(256) void k_gemm1f(const float* __restrict__ x,
                                                const float* __restrict__ W1,
                                                float* __restrict__ h1, int n) {
    __shared__ float Wt[16 * 516];
    int tid = threadIdx.x;
    for (int idx = tid; idx < 512 * 16; idx += 256) {
        int k = idx >> 4, c = idx & 15;
        Wt[c * 516 + k] = W1[idx];
    }
    __syncthreads();
    int wave = tid >> 6, lane = tid & 63;
    int c = lane & 15, r = lane >> 4;
    int row = blockIdx.x * 16 + wave * 4 + r;
    if (row >= n) return;
    const float4* xr = (const float4*)(x + (size_t)row * 512);
    const float4* wr = (const float4*)(Wt + c * 516);
    float4 acc = make_float4(0.f, 0.f, 0.f, 0.f);
#pragma unroll 8
    for (int k4 = 0; k4 < 128; ++k4) {
        float4 xv = xr[k4];
        float4 wv = wr[k4];
        acc.x = fmaf(xv.x, wv.x, acc.x);
        acc.y = fmaf(xv.y, wv.y, acc.y);
        acc.z = fmaf(xv.z, wv.z, acc.z);
        acc.w = fmaf(xv.w, wv.w, acc.w);
    }
    h1[(size_t)row * 16 + c] = (acc.x + acc.y) + (acc.z + acc.w);
}
template <int CH>
__global__ void k_self_init(const float* __restrict__ dinv, const float* __restrict__ h,
                            float* __restrict__ agg, int n) {
    int t = blockIdx.x * blockDim.x + threadIdx.x;
    int i = t / CH;
    if (i < n) { float dv = dinv[i]; agg[t] = dv * dv * h[t]; }
}
template <int CH>
__global__ void k_scatter(const int* __restrict__ src, const int* __restrict__ dst,
                          const float* __restrict__ w, const float* __restrict__ dinv,
                          const float* __restrict__ h, float* __restrict__ agg, int E) {
    int t = blockIdx.x * blockDim.x + threadIdx.x;
    int e = t / CH, c = t % CH;
    if (e >= E) return;
    int s = src[e], d = dst[e];
    float nrm = dinv[s] * w[e] * dinv[d];
    atomicAdd(&agg[(size_t)d * CH + c], nrm * h[(size_t)s * CH + c]);
}
__global__ __launch_bounds__(256) void k_gemm2(const float* __restrict__ agg1,
                                               const float* __restrict__ b1,
                                               const float* __restrict__ W2,
                                               float* __restrict__ h2, int n) {
    __shared__ float w2s[16 * 8];
    __shared__ float b1s[16];
    int tid = threadIdx.x;
    if (tid < 128) w2s[tid] = W2[tid];
    if (tid < 16) b1s[tid] = b1[tid];
    __syncthreads();
    int t = blockIdx.x * 256 + tid;
    int i = t >> 3, cc = t & 7;
    if (i >= n) return;
    const float* a = agg1 + (size_t)i * 16;
    float acc = 0.f;
#pragma unroll
    for (int k = 0; k < 16; ++k) {
        float v = fmaxf(a[k] + b1s[k], 0.f);
        acc = fmaf(v, w2s[k * 8 + cc], acc);
    }
    h2[(size_t)i * 8 + cc] = acc;
}
__global__ void k_logsoftmax(float* __restrict__ out, const float* __restrict__ b2, int n) {
    int i = blockIdx.x * blockDim.x + threadIdx.x;
    if (i >= n) return;
    float v[8];
#pragma unroll
    for (int c = 0; c < 8; ++c) v[c] = out[(size_t)i * 8 + c] + b2[c];
    float m = v[0];
#pragma unroll
    for (int c = 1; c < 8; ++c) m = fmaxf(m, v[c]);
    float s = 0.f;
#pragma unroll
    for (int c = 0; c < 8; ++c) s += expf(v[c] - m);
    float l = m + logf(s);
#pragma unroll
    for (int c = 0; c < 8; ++c) out[(size_t)i * 8 + c] = v[c] - l;
}
// ---------------------------------------------------------------------------

static inline size_t align64(size_t v) { return (v + 63) & ~(size_t)63; }

extern "C" void kernel_launch(void* const* d_in, const int* in_sizes, int n_in,
                              void* d_out, int out_size, void* d_ws, size_t ws_size,
                              hipStream_t stream) {
    const float* x  = (const float*)d_in[0];
    const int*   ei = (const int*)d_in[1];   // int32 per harness convention
    const float* ew = (const float*)d_in[2];
    const float* W1 = (const float*)d_in[3];
    const float* b1 = (const float*)d_in[4];
    const float* W2 = (const float*)d_in[5];
    const float* b2 = (const float*)d_in[6];
    float* out      = (float*)d_out;

    const int n = in_sizes[0] / 512;
    const int E = in_sizes[2];
    const int* src = ei;
    const int* dst = ei + E;

    const int B = 256;
    const int NBK = (n + 63) >> 6;
    const int chunk = (E + NBLK - 1) / NBLK;

    // ws: ebuf[E u2] | g1[16n fp16] | g2[8n fp16] | bh[NBLK*NBK] | tot | bs |
    //     dinv[n] | nrp[n+1] | W1h[8192 fp16]     (~37.7 MB at NBLK=1024)
    size_t off_ebuf = 0;
    size_t off_h1   = align64(off_ebuf + (size_t)E * 8);
    size_t off_h2   = align64(off_h1 + (size_t)16 * n * 2);
    size_t off_bh   = align64(off_h2 + (size_t)8 * n * 2);
    size_t off_tot  = align64(off_bh + (size_t)NBLK * NBK * 4);
    size_t off_bs   = align64(off_tot + (size_t)NBK * 4);
    size_t off_dinv = align64(off_bs + (size_t)(NBK + 1) * 4);
    size_t off_nrp  = align64(off_dinv + (size_t)n * 4);
    size_t off_w1h  = align64(off_nrp + (size_t)(n + 1) * 4);
    size_t need     = off_w1h + (size_t)512 * 16 * 2;

    if (ws_size >= need && NBK <= MAX_NBK && n <= (1 << 20)) {
        char* ws = (char*)d_ws;
        uint2*    ebuf = (uint2*)(ws + off_ebuf);
        __half*   g1   = (__half*)(ws + off_h1);
        __half*   g2   = (__half*)(ws + off_h2);
        int*      bh   = (int*)(ws + off_bh);
        int*      tot  = (int*)(ws + off_tot);
        int*      bs   = (int*)(ws + off_bs);
        float*    dinv = (float*)(ws + off_dinv);
        int*      nrp  = (int*)(ws + off_nrp);
        _Float16* w1h  = (_Float16*)(ws + off_w1h);

        k_prepW<<<32, B, 0, stream>>>(W1, w1h);
        k_hist<<<NBLK, B, 0, stream>>>(dst, bh, NBK, E, chunk);
        k_colscan<<<NBK, B, 0, stream>>>(bh, tot, NBK);
        k_scan_totals<<<1, B, 0, stream>>>(tot, bs, NBK, E);
        k_bin<<<NBLK, B, 0, stream>>>(src, dst, ew, bh, bs, ebuf, NBK, E, chunk);
        k_sortdeg<<<NBK, B, 0, stream>>>(ebuf, bs, nrp, dinv, n, NBK, E);

        k_gemm1<<<(n + 63) / 64, B, 0, stream>>>(x, w1h, dinv, g1, n);

        // ATTRIBUTION 2: both aggs launched 3x (idempotent).
        // T = t_agg16 + t_agg8 = (dur_us - 271.5) / 2. Revert next round.
        k_agg16g2<<<NBK, B, 0, stream>>>(nrp, ebuf, bs, dinv, g1, W2, b1, g2, n);
        k_agg16g2<<<NBK, B, 0, stream>>>(nrp, ebuf, bs, dinv, g1, W2, b1, g2, n);
        k_agg16g2<<<NBK, B, 0, stream>>>(nrp, ebuf, bs, dinv, g1, W2, b1, g2, n);
        k_agg8lsm<<<NBK, B, 0, stream>>>(nrp, ebuf, bs, dinv, g2, b2, out, n);
        k_agg8lsm<<<NBK, B, 0, stream>>>(nrp, ebuf, bs, dinv, g2, b2, out, n);
        k_agg8lsm<<<NBK, B, 0, stream>>>(nrp, ebuf, bs, dinv, g2, b2, out, n);
    } else {
        // fallback: atomic-scatter path (33n floats), fp32 everywhere
        float* deg  = (float*)d_ws;
        float* h1   = deg + n;
        float* h2   = h1;
        float* agg1 = h1 + (size_t)16 * n;
        int gn = (n + B - 1) / B, gE = (E + B - 1) / B;

        k_init_deg<<<gn, B, 0, stream>>>(deg, n);
        k_deg_scatter<<<gE, B, 0, stream>>>(dst, ew, deg, E);
        k_rsqrt_inplace<<<gn, B, 0, stream>>>(deg, n);
        k_gemm1f<<<(n + 15) / 16, B, 0, stream>>>(x, W1, h1, n);
        k_self_init<16><<<((size_t)16 * n + B - 1) / B, B, 0, stream>>>(deg, h1, agg1, n);
        k_scatter<16><<<((size_t)16 * E + B - 1) / B, B, 0, stream>>>(src, dst, ew, deg, h1, agg1, E);
        k_gemm2<<<((size_t)8 * n + B - 1) / B, B, 0, stream>>>(agg1, b1, W2, h2, n);
        k_self_init<8><<<((size_t)8 * n + B - 1) / B, B, 0, stream>>>(deg, h2, out, n);
        k_scatter<8><<<((size_t)8 * E + B - 1) / B, B, 0, stream>>>(src, dst, ew, deg, h2, out, E);
        k_logsoftmax<<<gn, B, 0, stream>>>(out, b2, n);
    }
}

// Round 18
// 248.269 us; speedup vs baseline: 1.7633x; 1.7633x over previous
//
#include <hip/hip_runtime.h>
#include <hip/hip_bf16.h>
#include <hip/hip_fp16.h>
#include <math.h>

// ---------------------------------------------------------------------------
// 2-layer GCN (PyG GCNConv), fp32 compute, fp16 intermediates (L2-resident).
// Bucket sort (atomic-free) -> per-node CSR -> register-gather aggregation.
// Normalization factored: g = dinv*h; RAW edge weights; dinv[d] in epilogues.
// Measured: gemm1 38.5us (HBM floor); aggs 83us (round 17 attribution);
// build pipeline + ~115us harness ws-poison fill = rest.
// Round 18: aggs restructured — thread q of node l takes edge subset
// e0+q::4, loads the FULL g-row per edge (2x/1x uint4), partials reduced
// across the 4 lanes via shfl_xor butterfly (no LDS atomics, ebuf read once
// per edge instead of 4x, serial chain 32 -> 8 iterations).
// edge_index arrives as int32 (harness converts integer inputs to int32).
// ---------------------------------------------------------------------------

#define NBLK 1024       // blocks in hist/bin passes (4/CU -> 16 waves/CU)
#define MAX_NBK 2048    // max buckets (n <= 131072); also pack limit n<2^20
#define CAP_SORTED 3072 // max bucket size for LDS-staged sort (avg 2048)

typedef _Float16 half8 __attribute__((ext_vector_type(8)));
typedef __fp16 fp16x2 __attribute__((ext_vector_type(2)));
typedef float f32x4 __attribute__((ext_vector_type(4)));

#define XPITCH 136      // LDS row pitch in fp16 (272B -> 2-way banks, free)

__device__ __forceinline__ float2 h2f(unsigned u) {
    __half2 h = *reinterpret_cast<__half2*>(&u);
    return __half22float2(h);
}

// Pass A: per-block histogram of dst>>6 over this block's edge chunk.
__global__ __launch_bounds__(256) void k_hist(const int* __restrict__ dst,
                                              int* __restrict__ bh,
                                              int NBK, int E, int chunk) {
    __shared__ int hist[MAX_NBK];
    int blk = blockIdx.x, tid = threadIdx.x;
    for (int b = tid; b < NBK; b += 256) hist[b] = 0;
    __syncthreads();
    int lo = blk * chunk, hi = min(lo + chunk, E);
    for (int e = lo + tid; e < hi; e += 256) atomicAdd(&hist[dst[e] >> 6], 1);
    __syncthreads();
    for (int b = tid; b < NBK; b += 256) bh[(size_t)blk * NBK + b] = hist[b];
}

// Pass B1: per-bucket exclusive scan over the NBLK block counts (in place);
// each thread owns 4 consecutive rows (NBLK = 4*256).
__global__ __launch_bounds__(256) void k_colscan(int* __restrict__ bh,
                                                 int* __restrict__ totals, int NBK) {
    __shared__ int s[256];
    int b = blockIdx.x, t = threadIdx.x;
    int v0 = bh[(size_t)(4 * t + 0) * NBK + b];
    int v1 = bh[(size_t)(4 * t + 1) * NBK + b];
    int v2 = bh[(size_t)(4 * t + 2) * NBK + b];
    int v3 = bh[(size_t)(4 * t + 3) * NBK + b];
    int lsum = v0 + v1 + v2 + v3;
    s[t] = lsum;
    __syncthreads();
    for (int off = 1; off < 256; off <<= 1) {
        int u = (t >= off) ? s[t - off] : 0;
        __syncthreads();
        s[t] += u;
        __syncthreads();
    }
    int pre = s[t] - lsum;
    bh[(size_t)(4 * t + 0) * NBK + b] = pre;
    bh[(size_t)(4 * t + 1) * NBK + b] = pre + v0;
    bh[(size_t)(4 * t + 2) * NBK + b] = pre + v0 + v1;
    bh[(size_t)(4 * t + 3) * NBK + b] = pre + v0 + v1 + v2;
    if (t == 255) totals[b] = s[255];
}

// Pass B2: exclusive scan of bucket totals -> bucketStart[NBK+1].
__global__ __launch_bounds__(256) void k_scan_totals(const int* __restrict__ totals,
                                                     int* __restrict__ bs,
                                                     int NBK, int E) {
    __shared__ int s[256];
    int t = threadIdx.x;
    int chunk = (NBK + 255) >> 8;
    int lo = t * chunk, hi = min(lo + chunk, NBK);
    int acc = 0;
    for (int i = lo; i < hi; ++i) acc += totals[i];
    s[t] = acc;
    __syncthreads();
    for (int off = 1; off < 256; off <<= 1) {
        int u = (t >= off) ? s[t - off] : 0;
        __syncthreads();
        s[t] += u;
        __syncthreads();
    }
    int pre = (t == 0) ? 0 : s[t - 1];
    for (int i = lo; i < hi; ++i) { bs[i] = pre; pre += totals[i]; }
    if (t == 0) bs[NBK] = E;
}

// Pass C: scatter edges into bucket regions (exclusive slices -> LDS cursors,
// zero global atomics). Edge packed: src | dstlow<<20, raw weight.
__global__ __launch_bounds__(256) void k_bin(const int* __restrict__ src,
                                             const int* __restrict__ dst,
                                             const float* __restrict__ w,
                                             const int* __restrict__ bh,
                                             const int* __restrict__ bs,
                                             uint2* __restrict__ ebuf,
                                             int NBK, int E, int chunk) {
    __shared__ int cur[MAX_NBK];
    int blk = blockIdx.x, tid = threadIdx.x;
    for (int b = tid; b < NBK; b += 256)
        cur[b] = bs[b] + bh[(size_t)blk * NBK + b];
    __syncthreads();
    int lo = blk * chunk, hi = min(lo + chunk, E);
    for (int e = lo + tid; e < hi; e += 256) {
        int d = dst[e];
        int b = d >> 6;
        int pos = atomicAdd(&cur[b], 1);  // LDS atomic (few collisions)
        ebuf[pos] = make_uint2((unsigned)src[e] | ((unsigned)(d & 63) << 20),
                               __float_as_uint(w[e]));
    }
}

// Pass D: within-bucket counting sort by dl (LDS-staged, in place) -> full
// per-node CSR. Also computes deg -> dinv and node rowptr. Buckets larger
// than CAP_SORTED are left unsorted (agg kernels fall back for those).
__global__ __launch_bounds__(256) void k_sortdeg(uint2* __restrict__ ebuf,
                                                 const int* __restrict__ bs,
                                                 int* __restrict__ nrp,
                                                 float* __restrict__ dinv,
                                                 int n, int NBK, int E) {
    __shared__ uint2 stage[CAP_SORTED];
    __shared__ int cnt[64];
    __shared__ float dw[64];
    __shared__ int cur[64];
    int b = blockIdx.x, tid = threadIdx.x;
    if (tid < 64) { cnt[tid] = 0; dw[tid] = 1.0f; }  // self-loop weight 1
    __syncthreads();
    int e0 = bs[b], e1 = bs[b + 1];
    int m = e1 - e0;
    bool sorted = (m <= CAP_SORTED);
    if (sorted) {
        for (int i = tid; i < m; i += 256) {
            uint2 p = ebuf[e0 + i];
            stage[i] = p;
            int dl = p.x >> 20;
            atomicAdd(&cnt[dl], 1);
            atomicAdd(&dw[dl], __uint_as_float(p.y));
        }
    } else {
        for (int i = tid; i < m; i += 256) {
            uint2 p = ebuf[e0 + i];
            int dl = p.x >> 20;
            atomicAdd(&cnt[dl], 1);
            atomicAdd(&dw[dl], __uint_as_float(p.y));
        }
    }
    __syncthreads();
    if (tid < 64) {
        int v = cnt[tid], x = v;
#pragma unroll
        for (int off = 1; off < 64; off <<= 1) {
            int y = __shfl_up(x, off);
            if (tid >= off) x += y;
        }
        int pre = x - v;
        cur[tid] = pre;
        int node = b * 64 + tid;
        if (node < n) {
            nrp[node] = e0 + pre;
            dinv[node] = rsqrtf(dw[tid]);
        }
    }
    if (b == NBK - 1 && tid == 0) nrp[n] = E;
    __syncthreads();
    if (sorted) {
        for (int i = tid; i < m; i += 256) {
            uint2 p = stage[i];
            int dl = p.x >> 20;
            int pos = atomicAdd(&cur[dl], 1);
            ebuf[e0 + pos] = p;
        }
    }
}

// W1 [512][16] fp32 -> W1h [16][512] fp16 (col-major for 16B B-frag loads).
__global__ __launch_bounds__(256) void k_prepW(const float* __restrict__ W1,
                                               _Float16* __restrict__ W1h) {
    int idx = blockIdx.x * 256 + threadIdx.x;
    if (idx < 512 * 16) {
        int k = idx >> 4, c = idx & 15;
        W1h[c * 512 + k] = (_Float16)W1[idx];
    }
}

// g1 = dinv * (x @ W1) via MFMA f32_16x16x32_f16, LDS-staged coalesced A.
// Measured round 15: ~38.5us (~HBM floor for 205MB x read) — do not touch.
__global__ __launch_bounds__(256) void k_gemm1(const float* __restrict__ x,
                                               const _Float16* __restrict__ W1h,
                                               const float* __restrict__ dinv,
                                               __half* __restrict__ g1, int n) {
    __shared__ _Float16 xlds[64 * XPITCH];
    int tid = threadIdx.x;
    int wave = tid >> 6, lane = tid & 63;
    int col = lane & 15;
    int kgrp = lane >> 4;
    const half8* wcol = (const half8*)(W1h + (size_t)col * 512);
    half8 bfrag[16];
#pragma unroll
    for (int t = 0; t < 16; ++t) bfrag[t] = wcol[t * 4 + kgrp];

    int rbase = blockIdx.x * 64;
    if (rbase >= n) return;
    int srow = tid >> 5;
    int sc4  = tid & 31;
    int rowl = wave * 16 + col;
    f32x4 acc = {0.f, 0.f, 0.f, 0.f};
#pragma unroll
    for (int c = 0; c < 4; ++c) {
#pragma unroll
        for (int i = 0; i < 8; ++i) {
            int row = srow + i * 8;
            int grow = min(rbase + row, n - 1);
            float4 v = *(const float4*)(x + (size_t)grow * 512 + c * 128 + sc4 * 4);
            union { fp16x2 h[2]; uint2 u; } pk;
            pk.h[0] = __builtin_amdgcn_cvt_pkrtz(v.x, v.y);
            pk.h[1] = __builtin_amdgcn_cvt_pkrtz(v.z, v.w);
            *(uint2*)(&xlds[row * XPITCH + sc4 * 4]) = pk.u;
        }
        __syncthreads();
#pragma unroll
        for (int s = 0; s < 4; ++s) {
            half8 a = *(const half8*)(&xlds[rowl * XPITCH + s * 32 + kgrp * 8]);
            acc = __builtin_amdgcn_mfma_f32_16x16x32_f16(a, bfrag[c * 4 + s], acc, 0, 0, 0);
        }
        __syncthreads();
    }
#pragma unroll
    for (int r = 0; r < 4; ++r) {
        int node = rbase + wave * 16 + kgrp * 4 + r;
        if (node < n) {
            float dv = dinv[node];
            g1[(size_t)node * 16 + col] = __float2half(acc[r] * dv);
        }
    }
}

// Layer-1 aggregation: thread q of node l handles edges e0+q::4, loading the
// FULL 32B g1 row per edge; 4-lane shfl_xor butterfly combines partials.
// Fused gemm2 epilogue: g2 = dinv * (relu(dinv*acc + b1) @ W2).
__global__ __launch_bounds__(256) void k_agg16g2(const int* __restrict__ nrp,
                                                 const uint2* __restrict__ ebuf,
                                                 const int* __restrict__ bs,
                                                 const float* __restrict__ dinv,
                                                 const __half* __restrict__ g1,
                                                 const float* __restrict__ W2,
                                                 const float* __restrict__ b1,
                                                 __half* __restrict__ g2, int n) {
    __shared__ float acc[64 * 17];
    __shared__ float w2s[16 * 8];
    __shared__ float b1s[16];
    int b = blockIdx.x, tid = threadIdx.x;
    int nodeBase = b * 64;
    if (tid < 128) w2s[tid] = W2[tid];
    if (tid < 16) b1s[tid] = b1[tid];
    int e0b = bs[b], e1b = bs[b + 1];
    int m = e1b - e0b;
    if (m <= CAP_SORTED) {
        int l = tid >> 2, q = tid & 3;
        int node = nodeBase + l;
        float r[16];
#pragma unroll
        for (int k = 0; k < 16; ++k) r[k] = 0.f;
        int e = 0, eE = 0;
        if (node < n) {
            e = nrp[node] + q;
            eE = nrp[node + 1];
            if (q == 0) {  // self contribution (summed in by butterfly)
                const uint4* sr = (const uint4*)(g1 + (size_t)node * 16);
                uint4 s0 = sr[0], s1 = sr[1];
                float2 f;
                f = h2f(s0.x); r[0] = f.x;  r[1] = f.y;
                f = h2f(s0.y); r[2] = f.x;  r[3] = f.y;
                f = h2f(s0.z); r[4] = f.x;  r[5] = f.y;
                f = h2f(s0.w); r[6] = f.x;  r[7] = f.y;
                f = h2f(s1.x); r[8] = f.x;  r[9] = f.y;
                f = h2f(s1.y); r[10] = f.x; r[11] = f.y;
                f = h2f(s1.z); r[12] = f.x; r[13] = f.y;
                f = h2f(s1.w); r[14] = f.x; r[15] = f.y;
            }
        }
        for (; e < eE; e += 4) {
            uint2 p = ebuf[e];
            float wE = __uint_as_float(p.y);
            unsigned s = p.x & 0xFFFFF;
            const uint4* hr = (const uint4*)(g1 + (size_t)s * 16);
            uint4 a0 = hr[0], a1 = hr[1];
            float2 f;
            f = h2f(a0.x); r[0]  = fmaf(wE, f.x, r[0]);  r[1]  = fmaf(wE, f.y, r[1]);
            f = h2f(a0.y); r[2]  = fmaf(wE, f.x, r[2]);  r[3]  = fmaf(wE, f.y, r[3]);
            f = h2f(a0.z); r[4]  = fmaf(wE, f.x, r[4]);  r[5]  = fmaf(wE, f.y, r[5]);
            f = h2f(a0.w); r[6]  = fmaf(wE, f.x, r[6]);  r[7]  = fmaf(wE, f.y, r[7]);
            f = h2f(a1.x); r[8]  = fmaf(wE, f.x, r[8]);  r[9]  = fmaf(wE, f.y, r[9]);
            f = h2f(a1.y); r[10] = fmaf(wE, f.x, r[10]); r[11] = fmaf(wE, f.y, r[11]);
            f = h2f(a1.z); r[12] = fmaf(wE, f.x, r[12]); r[13] = fmaf(wE, f.y, r[13]);
            f = h2f(a1.w); r[14] = fmaf(wE, f.x, r[14]); r[15] = fmaf(wE, f.y, r[15]);
        }
        // butterfly stage 1 (xor 1): bit0=0 keeps ch0-7, bit0=1 keeps ch8-15
        float s8[8];
#pragma unroll
        for (int k = 0; k < 8; ++k) {
            float tlo = __shfl_xor(r[k], 1);
            float thi = __shfl_xor(r[k + 8], 1);
            s8[k] = (q & 1) ? (r[k + 8] + thi) : (r[k] + tlo);
        }
        // butterfly stage 2 (xor 2): bit1 selects 4-block
        float s4[4];
#pragma unroll
        for (int k = 0; k < 4; ++k) {
            float tlo = __shfl_xor(s8[k], 2);
            float thi = __shfl_xor(s8[k + 4], 2);
            s4[k] = (q & 2) ? (s8[k + 4] + thi) : (s8[k] + tlo);
        }
        if (node < n) {
            int chbase = (q & 1) * 8 + ((q >> 1) & 1) * 4;
            float* ar = &acc[l * 17 + chbase];
            ar[0] = s4[0]; ar[1] = s4[1]; ar[2] = s4[2]; ar[3] = s4[3];
        }
    } else {
        for (int o = tid; o < 64 * 16; o += 256) {
            int l = o >> 4, c = o & 15;
            int node = nodeBase + l;
            float v = 0.f;
            if (node < n) v = __half2float(g1[(size_t)node * 16 + c]);
            acc[l * 17 + c] = v;
        }
        __syncthreads();
        for (int e = e0b + tid; e < e1b; e += 256) {
            uint2 p = ebuf[e];
            int s = p.x & 0xFFFFF;
            int dl = p.x >> 20;
            float wE = __uint_as_float(p.y);
            const uint4* hr = (const uint4*)(g1 + (size_t)s * 16);
            uint4 q0 = hr[0], q1 = hr[1];
            float* ar = &acc[dl * 17];
            float2 f;
            f = h2f(q0.x); atomicAdd(ar + 0,  wE * f.x); atomicAdd(ar + 1,  wE * f.y);
            f = h2f(q0.y); atomicAdd(ar + 2,  wE * f.x); atomicAdd(ar + 3,  wE * f.y);
            f = h2f(q0.z); atomicAdd(ar + 4,  wE * f.x); atomicAdd(ar + 5,  wE * f.y);
            f = h2f(q0.w); atomicAdd(ar + 6,  wE * f.x); atomicAdd(ar + 7,  wE * f.y);
            f = h2f(q1.x); atomicAdd(ar + 8,  wE * f.x); atomicAdd(ar + 9,  wE * f.y);
            f = h2f(q1.y); atomicAdd(ar + 10, wE * f.x); atomicAdd(ar + 11, wE * f.y);
            f = h2f(q1.z); atomicAdd(ar + 12, wE * f.x); atomicAdd(ar + 13, wE * f.y);
            f = h2f(q1.w); atomicAdd(ar + 14, wE * f.x); atomicAdd(ar + 15, wE * f.y);
        }
    }
    __syncthreads();
    // fused gemm2: g2[64x8] = dinv * (relu(dinv*acc + b1) @ W2)
    for (int o = tid; o < 64 * 8; o += 256) {
        int l = o >> 3, cc = o & 7;
        int node = nodeBase + l;
        if (node >= n) continue;
        float dv = dinv[node];
        float s = 0.f;
#pragma unroll
        for (int k = 0; k < 16; ++k) {
            float v = fmaxf(fmaf(dv, acc[l * 17 + k], b1s[k]), 0.f);
            s = fmaf(v, w2s[k * 8 + cc], s);
        }
        g2[(size_t)node * 8 + cc] = __float2half(s * dv);
    }
}

// Layer-2 aggregation: edge-quartered, full 16B row per edge, butterfly.
// Epilogue: v = dinv[d]*acc + b2 -> log_softmax.
__global__ __launch_bounds__(256) void k_agg8lsm(const int* __restrict__ nrp,
                                                 const uint2* __restrict__ ebuf,
                                                 const int* __restrict__ bs,
                                                 const float* __restrict__ dinv,
                                                 const __half* __restrict__ g2,
                                                 const float* __restrict__ b2,
                                                 float* __restrict__ out, int n) {
    __shared__ float acc[64 * 9];
    __shared__ float b2s[8];
    int b = blockIdx.x, tid = threadIdx.x;
    int nodeBase = b * 64;
    if (tid < 8) b2s[tid] = b2[tid];
    int e0b = bs[b], e1b = bs[b + 1];
    int m = e1b - e0b;
    if (m <= CAP_SORTED) {
        int l = tid >> 2, q = tid & 3;
        int node = nodeBase + l;
        float r[8];
#pragma unroll
        for (int k = 0; k < 8; ++k) r[k] = 0.f;
        int e = 0, eE = 0;
        if (node < n) {
            e = nrp[node] + q;
            eE = nrp[node + 1];
            if (q == 0) {
                const uint4* sr = (const uint4*)(g2 + (size_t)node * 8);
                uint4 s0 = sr[0];
                float2 f;
                f = h2f(s0.x); r[0] = f.x; r[1] = f.y;
                f = h2f(s0.y); r[2] = f.x; r[3] = f.y;
                f = h2f(s0.z); r[4] = f.x; r[5] = f.y;
                f = h2f(s0.w); r[6] = f.x; r[7] = f.y;
            }
        }
        for (; e < eE; e += 4) {
            uint2 p = ebuf[e];
            float wE = __uint_as_float(p.y);
            unsigned s = p.x & 0xFFFFF;
            const uint4* hr = (const uint4*)(g2 + (size_t)s * 8);
            uint4 a0 = hr[0];
            float2 f;
            f = h2f(a0.x); r[0] = fmaf(wE, f.x, r[0]); r[1] = fmaf(wE, f.y, r[1]);
            f = h2f(a0.y); r[2] = fmaf(wE, f.x, r[2]); r[3] = fmaf(wE, f.y, r[3]);
            f = h2f(a0.z); r[4] = fmaf(wE, f.x, r[4]); r[5] = fmaf(wE, f.y, r[5]);
            f = h2f(a0.w); r[6] = fmaf(wE, f.x, r[6]); r[7] = fmaf(wE, f.y, r[7]);
        }
        // stage 1 (xor 1): bit0=0 keeps ch0-3, bit0=1 keeps ch4-7
        float s4[4];
#pragma unroll
        for (int k = 0; k < 4; ++k) {
            float tlo = __shfl_xor(r[k], 1);
            float thi = __shfl_xor(r[k + 4], 1);
            s4[k] = (q & 1) ? (r[k + 4] + thi) : (r[k] + tlo);
        }
        // stage 2 (xor 2): bit1 selects 2-block
        float s2[2];
#pragma unroll
        for (int k = 0; k < 2; ++k) {
            float tlo = __shfl_xor(s4[k], 2);
            float thi = __shfl_xor(s4[k + 2], 2);
            s2[k] = (q & 2) ? (s4[k + 2] + thi) : (s4[k] + tlo);
        }
        if (node < n) {
            int chbase = (q & 1) * 4 + ((q >> 1) & 1) * 2;
            acc[l * 9 + chbase] = s2[0];
            acc[l * 9 + chbase + 1] = s2[1];
        }
    } else {
        for (int o = tid; o < 64 * 8; o += 256) {
            int l = o >> 3, c = o & 7;
            int node = nodeBase + l;
            float v = 0.f;
            if (node < n) v = __half2float(g2[(size_t)node * 8 + c]);
            acc[l * 9 + c] = v;
        }
        __syncthreads();
        for (int e = e0b + tid; e < e1b; e += 256) {
            uint2 p = ebuf[e];
            int s = p.x & 0xFFFFF;
            int dl = p.x >> 20;
            float wE = __uint_as_float(p.y);
            const uint4* hr = (const uint4*)(g2 + (size_t)s * 8);
            uint4 q0 = hr[0];
            float* ar = &acc[dl * 9];
            float2 f;
            f = h2f(q0.x); atomicAdd(ar + 0, wE * f.x); atomicAdd(ar + 1, wE * f.y);
            f = h2f(q0.y); atomicAdd(ar + 2, wE * f.x); atomicAdd(ar + 3, wE * f.y);
            f = h2f(q0.z); atomicAdd(ar + 4, wE * f.x); atomicAdd(ar + 5, wE * f.y);
            f = h2f(q0.w); atomicAdd(ar + 6, wE * f.x); atomicAdd(ar + 7, wE * f.y);
        }
    }
    __syncthreads();
    if (tid < 64) {
        int node = nodeBase + tid;
        if (node < n) {
            float dv = dinv[node];
            float v[8];
#pragma unroll
            for (int cc = 0; cc < 8; ++cc) v[cc] = fmaf(dv, acc[tid * 9 + cc], b2s[cc]);
            float mx = v[0];
#pragma unroll
            for (int cc = 1; cc < 8; ++cc) mx = fmaxf(mx, v[cc]);
            float sum = 0.f;
#pragma unroll
            for (int cc = 0; cc < 8; ++cc) sum += expf(v[cc] - mx);
            float lg = mx + logf(sum);
#pragma unroll
            for (int cc = 0; cc < 8; ++cc) out[(size_t)node * 8 + cc] = v[cc] - lg;
        }
    }
}

// -------------------- fallback (atomic scatter, proven correct) ------------
__global__ void k_init_deg(float* __restrict__ deg, int n) {
    int i = blockIdx.x * blockDim.x + threadIdx.x;
    if (i < n) deg[i] = 1.0f;
}
__global__ void k_deg_scatter(const int* __restrict__ dst, const float* __restrict__ w,
                              float* __restrict__ deg, int E) {
    int e = blockIdx.x * blockDim.x + threadIdx.x;
    if (e < E) atomicAdd(&deg[dst[e]], w[e]);
}
__global__ void k_rsqrt_inplace(float* __restrict__ deg, int n) {
    int i = blockIdx.x * blockDim.x + threadIdx.x;
    if (i < n) { float d = deg[i]; deg[i] = d > 0.0f ? rsqrtf(d) : 0.0f; }
}
__global__ __launch_bounds__(256) void k_gemm1f(const float* __restrict__ x,
                                                const float* __restrict__ W1,
                                                float* __restrict__ h1, int n) {
    __shared__ float Wt[16 * 516];
    int tid = threadIdx.x;
    for (int idx = tid; idx < 512 * 16; idx += 256) {
        int k = idx >> 4, c = idx & 15;
        Wt[c * 516 + k] = W1[idx];
    }
    __syncthreads();
    int wave = tid >> 6, lane = tid & 63;
    int c = lane & 15, r = lane >> 4;
    int row = blockIdx.x * 16 + wave * 4 + r;
    if (row >= n) return;
    const float4* xr = (const float4*)(x + (size_t)row * 512);
    const float4* wr = (const float4*)(Wt + c * 516);
    float4 acc = make_float4(0.f, 0.f, 0.f, 0.f);
#pragma unroll 8
    for (int k4 = 0; k4 < 128; ++k4) {
        float4 xv = xr[k4];
        float4 wv = wr[k4];
        acc.x = fmaf(xv.x, wv.x, acc.x);
        acc.y = fmaf(xv.y, wv.y, acc.y);
        acc.z = fmaf(xv.z, wv.z, acc.z);
        acc.w = fmaf(xv.w, wv.w, acc.w);
    }
    h1[(size_t)row * 16 + c] = (acc.x + acc.y) + (acc.z + acc.w);
}
template <int CH>
__global__ void k_self_init(const float* __restrict__ dinv, const float* __restrict__ h,
                            float* __restrict__ agg, int n) {
    int t = blockIdx.x * blockDim.x + threadIdx.x;
    int i = t / CH;
    if (i < n) { float dv = dinv[i]; agg[t] = dv * dv * h[t]; }
}
template <int CH>
__global__ void k_scatter(const int* __restrict__ src, const int* __restrict__ dst,
                          const float* __restrict__ w, const float* __restrict__ dinv,
                          const float* __restrict__ h, float* __restrict__ agg, int E) {
    int t = blockIdx.x * blockDim.x + threadIdx.x;
    int e = t / CH, c = t % CH;
    if (e >= E) return;
    int s = src[e], d = dst[e];
    float nrm = dinv[s] * w[e] * dinv[d];
    atomicAdd(&agg[(size_t)d * CH + c], nrm * h[(size_t)s * CH + c]);
}
__global__ __launch_bounds__(256) void k_gemm2(const float* __restrict__ agg1,
                                               const float* __restrict__ b1,
                                               const float* __restrict__ W2,
                                               float* __restrict__ h2, int n) {
    __shared__ float w2s[16 * 8];
    __shared__ float b1s[16];
    int tid = threadIdx.x;
    if (tid < 128) w2s[tid] = W2[tid];
    if (tid < 16) b1s[tid] = b1[tid];
    __syncthreads();
    int t = blockIdx.x * 256 + tid;
    int i = t >> 3, cc = t & 7;
    if (i >= n) return;
    const float* a = agg1 + (size_t)i * 16;
    float acc = 0.f;
#pragma unroll
    for (int k = 0; k < 16; ++k) {
        float v = fmaxf(a[k] + b1s[k], 0.f);
        acc = fmaf(v, w2s[k * 8 + cc], acc);
    }
    h2[(size_t)i * 8 + cc] = acc;
}
__global__ void k_logsoftmax(float* __restrict__ out, const float* __restrict__ b2, int n) {
    int i = blockIdx.x * blockDim.x + threadIdx.x;
    if (i >= n) return;
    float v[8];
#pragma unroll
    for (int c = 0; c < 8; ++c) v[c] = out[(size_t)i * 8 + c] + b2[c];
    float m = v[0];
#pragma unroll
    for (int c = 1; c < 8; ++c) m = fmaxf(m, v[c]);
    float s = 0.f;
#pragma unroll
    for (int c = 0; c < 8; ++c) s += expf(v[c] - m);
    float l = m + logf(s);
#pragma unroll
    for (int c = 0; c < 8; ++c) out[(size_t)i * 8 + c] = v[c] - l;
}
// ---------------------------------------------------------------------------

static inline size_t align64(size_t v) { return (v + 63) & ~(size_t)63; }

extern "C" void kernel_launch(void* const* d_in, const int* in_sizes, int n_in,
                              void* d_out, int out_size, void* d_ws, size_t ws_size,
                              hipStream_t stream) {
    const float* x  = (const float*)d_in[0];
    const int*   ei = (const int*)d_in[1];   // int32 per harness convention
    const float* ew = (const float*)d_in[2];
    const float* W1 = (const float*)d_in[3];
    const float* b1 = (const float*)d_in[4];
    const float* W2 = (const float*)d_in[5];
    const float* b2 = (const float*)d_in[6];
    float* out      = (float*)d_out;

    const int n = in_sizes[0] / 512;
    const int E = in_sizes[2];
    const int* src = ei;
    const int* dst = ei + E;

    const int B = 256;
    const int NBK = (n + 63) >> 6;
    const int chunk = (E + NBLK - 1) / NBLK;

    // ws: ebuf[E u2] | g1[16n fp16] | g2[8n fp16] | bh[NBLK*NBK] | tot | bs |
    //     dinv[n] | nrp[n+1] | W1h[8192 fp16]     (~37.7 MB at NBLK=1024)
    size_t off_ebuf = 0;
    size_t off_h1   = align64(off_ebuf + (size_t)E * 8);
    size_t off_h2   = align64(off_h1 + (size_t)16 * n * 2);
    size_t off_bh   = align64(off_h2 + (size_t)8 * n * 2);
    size_t off_tot  = align64(off_bh + (size_t)NBLK * NBK * 4);
    size_t off_bs   = align64(off_tot + (size_t)NBK * 4);
    size_t off_dinv = align64(off_bs + (size_t)(NBK + 1) * 4);
    size_t off_nrp  = align64(off_dinv + (size_t)n * 4);
    size_t off_w1h  = align64(off_nrp + (size_t)(n + 1) * 4);
    size_t need     = off_w1h + (size_t)512 * 16 * 2;

    if (ws_size >= need && NBK <= MAX_NBK && n <= (1 << 20)) {
        char* ws = (char*)d_ws;
        uint2*    ebuf = (uint2*)(ws + off_ebuf);
        __half*   g1   = (__half*)(ws + off_h1);
        __half*   g2   = (__half*)(ws + off_h2);
        int*      bh   = (int*)(ws + off_bh);
        int*      tot  = (int*)(ws + off_tot);
        int*      bs   = (int*)(ws + off_bs);
        float*    dinv = (float*)(ws + off_dinv);
        int*      nrp  = (int*)(ws + off_nrp);
        _Float16* w1h  = (_Float16*)(ws + off_w1h);

        k_prepW<<<32, B, 0, stream>>>(W1, w1h);
        k_hist<<<NBLK, B, 0, stream>>>(dst, bh, NBK, E, chunk);
        k_colscan<<<NBK, B, 0, stream>>>(bh, tot, NBK);
        k_scan_totals<<<1, B, 0, stream>>>(tot, bs, NBK, E);
        k_bin<<<NBLK, B, 0, stream>>>(src, dst, ew, bh, bs, ebuf, NBK, E, chunk);
        k_sortdeg<<<NBK, B, 0, stream>>>(ebuf, bs, nrp, dinv, n, NBK, E);

        k_gemm1<<<(n + 63) / 64, B, 0, stream>>>(x, w1h, dinv, g1, n);
        k_agg16g2<<<NBK, B, 0, stream>>>(nrp, ebuf, bs, dinv, g1, W2, b1, g2, n);
        k_agg8lsm<<<NBK, B, 0, stream>>>(nrp, ebuf, bs, dinv, g2, b2, out, n);
    } else {
        // fallback: atomic-scatter path (33n floats), fp32 everywhere
        float* deg  = (float*)d_ws;
        float* h1   = deg + n;
        float* h2   = h1;
        float* agg1 = h1 + (size_t)16 * n;
        int gn = (n + B - 1) / B, gE = (E + B - 1) / B;

        k_init_deg<<<gn, B, 0, stream>>>(deg, n);
        k_deg_scatter<<<gE, B, 0, stream>>>(dst, ew, deg, E);
        k_rsqrt_inplace<<<gn, B, 0, stream>>>(deg, n);
        k_gemm1f<<<(n + 15) / 16, B, 0, stream>>>(x, W1, h1, n);
        k_self_init<16><<<((size_t)16 * n + B - 1) / B, B, 0, stream>>>(deg, h1, agg1, n);
        k_scatter<16><<<((size_t)16 * E + B - 1) / B, B, 0, stream>>>(src, dst, ew, deg, h1, agg1, E);
        k_gemm2<<<((size_t)8 * n + B - 1) / B, B, 0, stream>>>(agg1, b1, W2, h2, n);
        k_self_init<8><<<((size_t)8 * n + B - 1) / B, B, 0, stream>>>(deg, h2, out, n);
        k_scatter<8><<<((size_t)8 * E + B - 1) / B, B, 0, stream>>>(src, dst, ew, deg, h2, out, E);
        k_logsoftmax<<<gn, B, 0, stream>>>(out, b2, n);
    }
}

// Round 19
// 228.788 us; speedup vs baseline: 1.9134x; 1.0852x over previous
//
#include <hip/hip_runtime.h>
#include <hip/hip_bf16.h>
#include <hip/hip_fp16.h>
#include <math.h>

// ---------------------------------------------------------------------------
// 2-layer GCN (PyG GCNConv), fp32 compute, fp16 intermediates (L2-resident).
// Bucket sort (atomic-free) -> per-node CSR -> register-gather aggregation.
// Normalization factored: g = dinv*h; RAW edge weights; dinv[d] in epilogues.
// Measured: gemm1 38.5us (HBM floor); aggs 83->~60us (round 18 butterfly).
// Round 19: (a) aggs at 8 threads/node (32 nodes/block, 3-stage shfl_xor
// butterfly, serial gather chain 8->4 iters); (b) colscan coalesced
// (16 buckets/block: consecutive lanes read consecutive columns; the old
// one-bucket-per-block layout made every dword its own cache line).
// edge_index arrives as int32 (harness converts integer inputs to int32).
// ---------------------------------------------------------------------------

#define NBLK 1024       // blocks in hist/bin passes (4/CU -> 16 waves/CU)
#define MAX_NBK 2048    // max buckets (n <= 131072); also pack limit n<2^20
#define CAP_SORTED 3072 // max bucket size for LDS-staged sort (avg 2048)

typedef _Float16 half8 __attribute__((ext_vector_type(8)));
typedef __fp16 fp16x2 __attribute__((ext_vector_type(2)));
typedef float f32x4 __attribute__((ext_vector_type(4)));

#define XPITCH 136      // LDS row pitch in fp16 (272B -> 2-way banks, free)

__device__ __forceinline__ float2 h2f(unsigned u) {
    __half2 h = *reinterpret_cast<__half2*>(&u);
    return __half22float2(h);
}

// Pass A: per-block histogram of dst>>6 over this block's edge chunk.
__global__ __launch_bounds__(256) void k_hist(const int* __restrict__ dst,
                                              int* __restrict__ bh,
                                              int NBK, int E, int chunk) {
    __shared__ int hist[MAX_NBK];
    int blk = blockIdx.x, tid = threadIdx.x;
    for (int b = tid; b < NBK; b += 256) hist[b] = 0;
    __syncthreads();
    int lo = blk * chunk, hi = min(lo + chunk, E);
    for (int e = lo + tid; e < hi; e += 256) atomicAdd(&hist[dst[e] >> 6], 1);
    __syncthreads();
    for (int b = tid; b < NBK; b += 256) bh[(size_t)blk * NBK + b] = hist[b];
}

// Pass B1: per-bucket exclusive scan over the NBLK block counts (in place).
// 16 buckets per block; thread (r,bk) owns 64 consecutive rows of bucket
// b0+bk. Consecutive lanes read consecutive columns -> coalesced lines.
__global__ __launch_bounds__(256) void k_colscan(int* __restrict__ bh,
                                                 int* __restrict__ totals, int NBK) {
    __shared__ int s[256];  // s[r*16+bk]
    int tid = threadIdx.x;
    int bk = tid & 15, r = tid >> 4;
    int b = blockIdx.x * 16 + bk;
    bool ok = (b < NBK);
    int base = r * 64;      // NBLK = 1024 = 16*64
    int lsum = 0;
    if (ok) {
        for (int j = 0; j < 64; ++j)
            lsum += bh[(size_t)(base + j) * NBK + b];
    }
    s[r * 16 + bk] = lsum;
    __syncthreads();
    int pre = 0;
    for (int i = 0; i < r; ++i) pre += s[i * 16 + bk];
    if (ok) {
        int run = pre;
        for (int j = 0; j < 64; ++j) {
            size_t idx = (size_t)(base + j) * NBK + b;
            int v = bh[idx];
            bh[idx] = run;
            run += v;
        }
        if (r == 15) totals[b] = run;
    }
}

// Pass B2: exclusive scan of bucket totals -> bucketStart[NBK+1].
__global__ __launch_bounds__(256) void k_scan_totals(const int* __restrict__ totals,
                                                     int* __restrict__ bs,
                                                     int NBK, int E) {
    __shared__ int s[256];
    int t = threadIdx.x;
    int chunk = (NBK + 255) >> 8;
    int lo = t * chunk, hi = min(lo + chunk, NBK);
    int acc = 0;
    for (int i = lo; i < hi; ++i) acc += totals[i];
    s[t] = acc;
    __syncthreads();
    for (int off = 1; off < 256; off <<= 1) {
        int u = (t >= off) ? s[t - off] : 0;
        __syncthreads();
        s[t] += u;
        __syncthreads();
    }
    int pre = (t == 0) ? 0 : s[t - 1];
    for (int i = lo; i < hi; ++i) { bs[i] = pre; pre += totals[i]; }
    if (t == 0) bs[NBK] = E;
}

// Pass C: scatter edges into bucket regions (exclusive slices -> LDS cursors,
// zero global atomics). Edge packed: src | dstlow<<20, raw weight.
__global__ __launch_bounds__(256) void k_bin(const int* __restrict__ src,
                                             const int* __restrict__ dst,
                                             const float* __restrict__ w,
                                             const int* __restrict__ bh,
                                             const int* __restrict__ bs,
                                             uint2* __restrict__ ebuf,
                                             int NBK, int E, int chunk) {
    __shared__ int cur[MAX_NBK];
    int blk = blockIdx.x, tid = threadIdx.x;
    for (int b = tid; b < NBK; b += 256)
        cur[b] = bs[b] + bh[(size_t)blk * NBK + b];
    __syncthreads();
    int lo = blk * chunk, hi = min(lo + chunk, E);
    for (int e = lo + tid; e < hi; e += 256) {
        int d = dst[e];
        int b = d >> 6;
        int pos = atomicAdd(&cur[b], 1);  // LDS atomic (few collisions)
        ebuf[pos] = make_uint2((unsigned)src[e] | ((unsigned)(d & 63) << 20),
                               __float_as_uint(w[e]));
    }
}

// Pass D: within-bucket counting sort by dl (LDS-staged, in place) -> full
// per-node CSR. Also computes deg -> dinv and node rowptr. Buckets larger
// than CAP_SORTED are left unsorted (agg kernels fall back for those).
__global__ __launch_bounds__(256) void k_sortdeg(uint2* __restrict__ ebuf,
                                                 const int* __restrict__ bs,
                                                 int* __restrict__ nrp,
                                                 float* __restrict__ dinv,
                                                 int n, int NBK, int E) {
    __shared__ uint2 stage[CAP_SORTED];
    __shared__ int cnt[64];
    __shared__ float dw[64];
    __shared__ int cur[64];
    int b = blockIdx.x, tid = threadIdx.x;
    if (tid < 64) { cnt[tid] = 0; dw[tid] = 1.0f; }  // self-loop weight 1
    __syncthreads();
    int e0 = bs[b], e1 = bs[b + 1];
    int m = e1 - e0;
    bool sorted = (m <= CAP_SORTED);
    if (sorted) {
        for (int i = tid; i < m; i += 256) {
            uint2 p = ebuf[e0 + i];
            stage[i] = p;
            int dl = p.x >> 20;
            atomicAdd(&cnt[dl], 1);
            atomicAdd(&dw[dl], __uint_as_float(p.y));
        }
    } else {
        for (int i = tid; i < m; i += 256) {
            uint2 p = ebuf[e0 + i];
            int dl = p.x >> 20;
            atomicAdd(&cnt[dl], 1);
            atomicAdd(&dw[dl], __uint_as_float(p.y));
        }
    }
    __syncthreads();
    if (tid < 64) {
        int v = cnt[tid], x = v;
#pragma unroll
        for (int off = 1; off < 64; off <<= 1) {
            int y = __shfl_up(x, off);
            if (tid >= off) x += y;
        }
        int pre = x - v;
        cur[tid] = pre;
        int node = b * 64 + tid;
        if (node < n) {
            nrp[node] = e0 + pre;
            dinv[node] = rsqrtf(dw[tid]);
        }
    }
    if (b == NBK - 1 && tid == 0) nrp[n] = E;
    __syncthreads();
    if (sorted) {
        for (int i = tid; i < m; i += 256) {
            uint2 p = stage[i];
            int dl = p.x >> 20;
            int pos = atomicAdd(&cur[dl], 1);
            ebuf[e0 + pos] = p;
        }
    }
}

// W1 [512][16] fp32 -> W1h [16][512] fp16 (col-major for 16B B-frag loads).
__global__ __launch_bounds__(256) void k_prepW(const float* __restrict__ W1,
                                               _Float16* __restrict__ W1h) {
    int idx = blockIdx.x * 256 + threadIdx.x;
    if (idx < 512 * 16) {
        int k = idx >> 4, c = idx & 15;
        W1h[c * 512 + k] = (_Float16)W1[idx];
    }
}

// g1 = dinv * (x @ W1) via MFMA f32_16x16x32_f16, LDS-staged coalesced A.
// Measured round 15: ~38.5us (~HBM floor for 205MB x read) — do not touch.
__global__ __launch_bounds__(256) void k_gemm1(const float* __restrict__ x,
                                               const _Float16* __restrict__ W1h,
                                               const float* __restrict__ dinv,
                                               __half* __restrict__ g1, int n) {
    __shared__ _Float16 xlds[64 * XPITCH];
    int tid = threadIdx.x;
    int wave = tid >> 6, lane = tid & 63;
    int col = lane & 15;
    int kgrp = lane >> 4;
    const half8* wcol = (const half8*)(W1h + (size_t)col * 512);
    half8 bfrag[16];
#pragma unroll
    for (int t = 0; t < 16; ++t) bfrag[t] = wcol[t * 4 + kgrp];

    int rbase = blockIdx.x * 64;
    if (rbase >= n) return;
    int srow = tid >> 5;
    int sc4  = tid & 31;
    int rowl = wave * 16 + col;
    f32x4 acc = {0.f, 0.f, 0.f, 0.f};
#pragma unroll
    for (int c = 0; c < 4; ++c) {
#pragma unroll
        for (int i = 0; i < 8; ++i) {
            int row = srow + i * 8;
            int grow = min(rbase + row, n - 1);
            float4 v = *(const float4*)(x + (size_t)grow * 512 + c * 128 + sc4 * 4);
            union { fp16x2 h[2]; uint2 u; } pk;
            pk.h[0] = __builtin_amdgcn_cvt_pkrtz(v.x, v.y);
            pk.h[1] = __builtin_amdgcn_cvt_pkrtz(v.z, v.w);
            *(uint2*)(&xlds[row * XPITCH + sc4 * 4]) = pk.u;
        }
        __syncthreads();
#pragma unroll
        for (int s = 0; s < 4; ++s) {
            half8 a = *(const half8*)(&xlds[rowl * XPITCH + s * 32 + kgrp * 8]);
            acc = __builtin_amdgcn_mfma_f32_16x16x32_f16(a, bfrag[c * 4 + s], acc, 0, 0, 0);
        }
        __syncthreads();
    }
#pragma unroll
    for (int r = 0; r < 4; ++r) {
        int node = rbase + wave * 16 + kgrp * 4 + r;
        if (node < n) {
            float dv = dinv[node];
            g1[(size_t)node * 16 + col] = __float2half(acc[r] * dv);
        }
    }
}

// Layer-1 aggregation: 32 nodes/block, 8 threads/node (edges e0+q::8, full
// 32B row per edge), 3-stage shfl_xor butterfly -> lane holds 2 channels.
// Fused gemm2 epilogue (exactly 1 output element per thread).
__global__ __launch_bounds__(256) void k_agg16g2(const int* __restrict__ nrp,
                                                 const uint2* __restrict__ ebuf,
                                                 const int* __restrict__ bs,
                                                 const float* __restrict__ dinv,
                                                 const __half* __restrict__ g1,
                                                 const float* __restrict__ W2,
                                                 const float* __restrict__ b1,
                                                 __half* __restrict__ g2, int n) {
    __shared__ float acc[32 * 17];
    __shared__ float w2s[16 * 8];
    __shared__ float b1s[16];
    int blk = blockIdx.x, tid = threadIdx.x;
    int nodeBase = blk * 32;
    if (tid < 128) w2s[tid] = W2[tid];
    if (tid < 16) b1s[tid] = b1[tid];
    int bucket = blk >> 1;
    int e0b = bs[bucket], e1b = bs[bucket + 1];
    int m = e1b - e0b;
    if (m <= CAP_SORTED) {
        int l = tid >> 3, q = tid & 7;
        int node = nodeBase + l;
        float r[16];
#pragma unroll
        for (int k = 0; k < 16; ++k) r[k] = 0.f;
        int e = 0, eE = 0;
        if (node < n) {
            e = nrp[node] + q;
            eE = nrp[node + 1];
            if (q == 0) {  // self contribution (summed in by butterfly)
                const uint4* sr = (const uint4*)(g1 + (size_t)node * 16);
                uint4 s0 = sr[0], s1 = sr[1];
                float2 f;
                f = h2f(s0.x); r[0] = f.x;  r[1] = f.y;
                f = h2f(s0.y); r[2] = f.x;  r[3] = f.y;
                f = h2f(s0.z); r[4] = f.x;  r[5] = f.y;
                f = h2f(s0.w); r[6] = f.x;  r[7] = f.y;
                f = h2f(s1.x); r[8] = f.x;  r[9] = f.y;
                f = h2f(s1.y); r[10] = f.x; r[11] = f.y;
                f = h2f(s1.z); r[12] = f.x; r[13] = f.y;
                f = h2f(s1.w); r[14] = f.x; r[15] = f.y;
            }
        }
        for (; e < eE; e += 8) {
            uint2 p = ebuf[e];
            float wE = __uint_as_float(p.y);
            unsigned s = p.x & 0xFFFFF;
            const uint4* hr = (const uint4*)(g1 + (size_t)s * 16);
            uint4 a0 = hr[0], a1 = hr[1];
            float2 f;
            f = h2f(a0.x); r[0]  = fmaf(wE, f.x, r[0]);  r[1]  = fmaf(wE, f.y, r[1]);
            f = h2f(a0.y); r[2]  = fmaf(wE, f.x, r[2]);  r[3]  = fmaf(wE, f.y, r[3]);
            f = h2f(a0.z); r[4]  = fmaf(wE, f.x, r[4]);  r[5]  = fmaf(wE, f.y, r[5]);
            f = h2f(a0.w); r[6]  = fmaf(wE, f.x, r[6]);  r[7]  = fmaf(wE, f.y, r[7]);
            f = h2f(a1.x); r[8]  = fmaf(wE, f.x, r[8]);  r[9]  = fmaf(wE, f.y, r[9]);
            f = h2f(a1.y); r[10] = fmaf(wE, f.x, r[10]); r[11] = fmaf(wE, f.y, r[11]);
            f = h2f(a1.z); r[12] = fmaf(wE, f.x, r[12]); r[13] = fmaf(wE, f.y, r[13]);
            f = h2f(a1.w); r[14] = fmaf(wE, f.x, r[14]); r[15] = fmaf(wE, f.y, r[15]);
        }
        // stage 1 (xor 1): bit0 keeps lower/upper 8 channels
        float s8[8];
#pragma unroll
        for (int k = 0; k < 8; ++k) {
            float tlo = __shfl_xor(r[k], 1);
            float thi = __shfl_xor(r[k + 8], 1);
            s8[k] = (q & 1) ? (r[k + 8] + thi) : (r[k] + tlo);
        }
        // stage 2 (xor 2): bit1 selects 4-block
        float s4[4];
#pragma unroll
        for (int k = 0; k < 4; ++k) {
            float tlo = __shfl_xor(s8[k], 2);
            float thi = __shfl_xor(s8[k + 4], 2);
            s4[k] = (q & 2) ? (s8[k + 4] + thi) : (s8[k] + tlo);
        }
        // stage 3 (xor 4): bit2 selects 2-block
        float s2[2];
#pragma unroll
        for (int k = 0; k < 2; ++k) {
            float tlo = __shfl_xor(s4[k], 4);
            float thi = __shfl_xor(s4[k + 2], 4);
            s2[k] = (q & 4) ? (s4[k + 2] + thi) : (s4[k] + tlo);
        }
        if (node < n) {
            int chbase = (q & 1) * 8 + ((q >> 1) & 1) * 4 + ((q >> 2) & 1) * 2;
            acc[l * 17 + chbase] = s2[0];
            acc[l * 17 + chbase + 1] = s2[1];
        }
    } else {
        for (int o = tid; o < 32 * 16; o += 256) {
            int l = o >> 4, c = o & 15;
            int node = nodeBase + l;
            float v = 0.f;
            if (node < n) v = __half2float(g1[(size_t)node * 16 + c]);
            acc[l * 17 + c] = v;
        }
        __syncthreads();
        int half = (blk & 1) * 32;
        for (int e = e0b + tid; e < e1b; e += 256) {
            uint2 p = ebuf[e];
            int dl = (int)(p.x >> 20) - half;
            if (dl < 0 || dl >= 32) continue;
            int s = p.x & 0xFFFFF;
            float wE = __uint_as_float(p.y);
            const uint4* hr = (const uint4*)(g1 + (size_t)s * 16);
            uint4 q0 = hr[0], q1 = hr[1];
            float* ar = &acc[dl * 17];
            float2 f;
            f = h2f(q0.x); atomicAdd(ar + 0,  wE * f.x); atomicAdd(ar + 1,  wE * f.y);
            f = h2f(q0.y); atomicAdd(ar + 2,  wE * f.x); atomicAdd(ar + 3,  wE * f.y);
            f = h2f(q0.z); atomicAdd(ar + 4,  wE * f.x); atomicAdd(ar + 5,  wE * f.y);
            f = h2f(q0.w); atomicAdd(ar + 6,  wE * f.x); atomicAdd(ar + 7,  wE * f.y);
            f = h2f(q1.x); atomicAdd(ar + 8,  wE * f.x); atomicAdd(ar + 9,  wE * f.y);
            f = h2f(q1.y); atomicAdd(ar + 10, wE * f.x); atomicAdd(ar + 11, wE * f.y);
            f = h2f(q1.z); atomicAdd(ar + 12, wE * f.x); atomicAdd(ar + 13, wE * f.y);
            f = h2f(q1.w); atomicAdd(ar + 14, wE * f.x); atomicAdd(ar + 15, wE * f.y);
        }
    }
    __syncthreads();
    // fused gemm2: one output element per thread (32 nodes x 8 cols)
    {
        int l = tid >> 3, cc = tid & 7;
        int node = nodeBase + l;
        if (node < n) {
            float dv = dinv[node];
            float s = 0.f;
#pragma unroll
            for (int k = 0; k < 16; ++k) {
                float v = fmaxf(fmaf(dv, acc[l * 17 + k], b1s[k]), 0.f);
                s = fmaf(v, w2s[k * 8 + cc], s);
            }
            g2[(size_t)node * 8 + cc] = __float2half(s * dv);
        }
    }
}

// Layer-2 aggregation: 32 nodes/block, 8 threads/node, 3-stage butterfly ->
// lane holds 1 channel. Fused +b2 and log_softmax epilogue.
__global__ __launch_bounds__(256) void k_agg8lsm(const int* __restrict__ nrp,
                                                 const uint2* __restrict__ ebuf,
                                                 const int* __restrict__ bs,
                                                 const float* __restrict__ dinv,
                                                 const __half* __restrict__ g2,
                                                 const float* __restrict__ b2,
                                                 float* __restrict__ out, int n) {
    __shared__ float acc[32 * 9];
    __shared__ float b2s[8];
    int blk = blockIdx.x, tid = threadIdx.x;
    int nodeBase = blk * 32;
    if (tid < 8) b2s[tid] = b2[tid];
    int bucket = blk >> 1;
    int e0b = bs[bucket], e1b = bs[bucket + 1];
    int m = e1b - e0b;
    if (m <= CAP_SORTED) {
        int l = tid >> 3, q = tid & 7;
        int node = nodeBase + l;
        float r[8];
#pragma unroll
        for (int k = 0; k < 8; ++k) r[k] = 0.f;
        int e = 0, eE = 0;
        if (node < n) {
            e = nrp[node] + q;
            eE = nrp[node + 1];
            if (q == 0) {
                const uint4* sr = (const uint4*)(g2 + (size_t)node * 8);
                uint4 s0 = sr[0];
                float2 f;
                f = h2f(s0.x); r[0] = f.x; r[1] = f.y;
                f = h2f(s0.y); r[2] = f.x; r[3] = f.y;
                f = h2f(s0.z); r[4] = f.x; r[5] = f.y;
                f = h2f(s0.w); r[6] = f.x; r[7] = f.y;
            }
        }
        for (; e < eE; e += 8) {
            uint2 p = ebuf[e];
            float wE = __uint_as_float(p.y);
            unsigned s = p.x & 0xFFFFF;
            const uint4* hr = (const uint4*)(g2 + (size_t)s * 8);
            uint4 a0 = hr[0];
            float2 f;
            f = h2f(a0.x); r[0] = fmaf(wE, f.x, r[0]); r[1] = fmaf(wE, f.y, r[1]);
            f = h2f(a0.y); r[2] = fmaf(wE, f.x, r[2]); r[3] = fmaf(wE, f.y, r[3]);
            f = h2f(a0.z); r[4] = fmaf(wE, f.x, r[4]); r[5] = fmaf(wE, f.y, r[5]);
            f = h2f(a0.w); r[6] = fmaf(wE, f.x, r[6]); r[7] = fmaf(wE, f.y, r[7]);
        }
        float s4[4];
#pragma unroll
        for (int k = 0; k < 4; ++k) {
            float tlo = __shfl_xor(r[k], 1);
            float thi = __shfl_xor(r[k + 4], 1);
            s4[k] = (q & 1) ? (r[k + 4] + thi) : (r[k] + tlo);
        }
        float s2[2];
#pragma unroll
        for (int k = 0; k < 2; ++k) {
            float tlo = __shfl_xor(s4[k], 2);
            float thi = __shfl_xor(s4[k + 2], 2);
            s2[k] = (q & 2) ? (s4[k + 2] + thi) : (s4[k] + tlo);
        }
        float s1;
        {
            float tlo = __shfl_xor(s2[0], 4);
            float thi = __shfl_xor(s2[1], 4);
            s1 = (q & 4) ? (s2[1] + thi) : (s2[0] + tlo);
        }
        if (node < n) {
            int ch = (q & 1) * 4 + ((q >> 1) & 1) * 2 + ((q >> 2) & 1);
            acc[l * 9 + ch] = s1;
        }
    } else {
        for (int o = tid; o < 32 * 8; o += 256) {
            int l = o >> 3, c = o & 7;
            int node = nodeBase + l;
            float v = 0.f;
            if (node < n) v = __half2float(g2[(size_t)node * 8 + c]);
            acc[l * 9 + c] = v;
        }
        __syncthreads();
        int half = (blk & 1) * 32;
        for (int e = e0b + tid; e < e1b; e += 256) {
            uint2 p = ebuf[e];
            int dl = (int)(p.x >> 20) - half;
            if (dl < 0 || dl >= 32) continue;
            int s = p.x & 0xFFFFF;
            float wE = __uint_as_float(p.y);
            const uint4* hr = (const uint4*)(g2 + (size_t)s * 8);
            uint4 q0 = hr[0];
            float* ar = &acc[dl * 9];
            float2 f;
            f = h2f(q0.x); atomicAdd(ar + 0, wE * f.x); atomicAdd(ar + 1, wE * f.y);
            f = h2f(q0.y); atomicAdd(ar + 2, wE * f.x); atomicAdd(ar + 3, wE * f.y);
            f = h2f(q0.z); atomicAdd(ar + 4, wE * f.x); atomicAdd(ar + 5, wE * f.y);
            f = h2f(q0.w); atomicAdd(ar + 6, wE * f.x); atomicAdd(ar + 7, wE * f.y);
        }
    }
    __syncthreads();
    if (tid < 32) {
        int node = nodeBase + tid;
        if (node < n) {
            float dv = dinv[node];
            float v[8];
#pragma unroll
            for (int cc = 0; cc < 8; ++cc) v[cc] = fmaf(dv, acc[tid * 9 + cc], b2s[cc]);
            float mx = v[0];
#pragma unroll
            for (int cc = 1; cc < 8; ++cc) mx = fmaxf(mx, v[cc]);
            float sum = 0.f;
#pragma unroll
            for (int cc = 0; cc < 8; ++cc) sum += expf(v[cc] - mx);
            float lg = mx + logf(sum);
#pragma unroll
            for (int cc = 0; cc < 8; ++cc) out[(size_t)node * 8 + cc] = v[cc] - lg;
        }
    }
}

// -------------------- fallback (atomic scatter, proven correct) ------------
__global__ void k_init_deg(float* __restrict__ deg, int n) {
    int i = blockIdx.x * blockDim.x + threadIdx.x;
    if (i < n) deg[i] = 1.0f;
}
__global__ void k_deg_scatter(const int* __restrict__ dst, const float* __restrict__ w,
                              float* __restrict__ deg, int E) {
    int e = blockIdx.x * blockDim.x + threadIdx.x;
    if (e < E) atomicAdd(&deg[dst[e]], w[e]);
}
__global__ void k_rsqrt_inplace(float* __restrict__ deg, int n) {
    int i = blockIdx.x * blockDim.x + threadIdx.x;
    if (i < n) { float d = deg[i]; deg[i] = d > 0.0f ? rsqrtf(d) : 0.0f; }
}
__global__ __launch_bounds__(256) void k_gemm1f(const float* __restrict__ x,
                                                const float* __restrict__ W1,
                                                float* __restrict__ h1, int n) {
    __shared__ float Wt[16 * 516];
    int tid = threadIdx.x;
    for (int idx = tid; idx < 512 * 16; idx += 256) {
        int k = idx >> 4, c = idx & 15;
        Wt[c * 516 + k] = W1[idx];
    }
    __syncthreads();
    int wave = tid >> 6, lane = tid & 63;
    int c = lane & 15, r = lane >> 4;
    int row = blockIdx.x * 16 + wave * 4 + r;
    if (row >= n) return;
    const float4* xr = (const float4*)(x + (size_t)row * 512);
    const float4* wr = (const float4*)(Wt + c * 516);
    float4 acc = make_float4(0.f, 0.f, 0.f, 0.f);
#pragma unroll 8
    for (int k4 = 0; k4 < 128; ++k4) {
        float4 xv = xr[k4];
        float4 wv = wr[k4];
        acc.x = fmaf(xv.x, wv.x, acc.x);
        acc.y = fmaf(xv.y, wv.y, acc.y);
        acc.z = fmaf(xv.z, wv.z, acc.z);
        acc.w = fmaf(xv.w, wv.w, acc.w);
    }
    h1[(size_t)row * 16 + c] = (acc.x + acc.y) + (acc.z + acc.w);
}
template <int CH>
__global__ void k_self_init(const float* __restrict__ dinv, const float* __restrict__ h,
                            float* __restrict__ agg, int n) {
    int t = blockIdx.x * blockDim.x + threadIdx.x;
    int i = t / CH;
    if (i < n) { float dv = dinv[i]; agg[t] = dv * dv * h[t]; }
}
template <int CH>
__global__ void k_scatter(const int* __restrict__ src, const int* __restrict__ dst,
                          const float* __restrict__ w, const float* __restrict__ dinv,
                          const float* __restrict__ h, float* __restrict__ agg, int E) {
    int t = blockIdx.x * blockDim.x + threadIdx.x;
    int e = t / CH, c = t % CH;
    if (e >= E) return;
    int s = src[e], d = dst[e];
    float nrm = dinv[s] * w[e] * dinv[d];
    atomicAdd(&agg[(size_t)d * CH + c], nrm * h[(size_t)s * CH + c]);
}
__global__ __launch_bounds__(256) void k_gemm2(const float* __restrict__ agg1,
                                               const float* __restrict__ b1,
                                               const float* __restrict__ W2,
                                               float* __restrict__ h2, int n) {
    __shared__ float w2s[16 * 8];
    __shared__ float b1s[16];
    int tid = threadIdx.x;
    if (tid < 128) w2s[tid] = W2[tid];
    if (tid < 16) b1s[tid] = b1[tid];
    __syncthreads();
    int t = blockIdx.x * 256 + tid;
    int i = t >> 3, cc = t & 7;
    if (i >= n) return;
    const float* a = agg1 + (size_t)i * 16;
    float acc = 0.f;
#pragma unroll
    for (int k = 0; k < 16; ++k) {
        float v = fmaxf(a[k] + b1s[k], 0.f);
        acc = fmaf(v, w2s[k * 8 + cc], acc);
    }
    h2[(size_t)i * 8 + cc] = acc;
}
__global__ void k_logsoftmax(float* __restrict__ out, const float* __restrict__ b2, int n) {
    int i = blockIdx.x * blockDim.x + threadIdx.x;
    if (i >= n) return;
    float v[8];
#pragma unroll
    for (int c = 0; c < 8; ++c) v[c] = out[(size_t)i * 8 + c] + b2[c];
    float m = v[0];
#pragma unroll
    for (int c = 1; c < 8; ++c) m = fmaxf(m, v[c]);
    float s = 0.f;
#pragma unroll
    for (int c = 0; c < 8; ++c) s += expf(v[c] - m);
    float l = m + logf(s);
#pragma unroll
    for (int c = 0; c < 8; ++c) out[(size_t)i * 8 + c] = v[c] - l;
}
// ---------------------------------------------------------------------------

static inline size_t align64(size_t v) { return (v + 63) & ~(size_t)63; }

extern "C" void kernel_launch(void* const* d_in, const int* in_sizes, int n_in,
                              void* d_out, int out_size, void* d_ws, size_t ws_size,
                              hipStream_t stream) {
    const float* x  = (const float*)d_in[0];
    const int*   ei = (const int*)d_in[1];   // int32 per harness convention
    const float* ew = (const float*)d_in[2];
    const float* W1 = (const float*)d_in[3];
    const float* b1 = (const float*)d_in[4];
    const float* W2 = (const float*)d_in[5];
    const float* b2 = (const float*)d_in[6];
    float* out      = (float*)d_out;

    const int n = in_sizes[0] / 512;
    const int E = in_sizes[2];
    const int* src = ei;
    const int* dst = ei + E;

    const int B = 256;
    const int NBK = (n + 63) >> 6;
    const int NB32 = (n + 31) >> 5;   // 32-node agg blocks
    const int chunk = (E + NBLK - 1) / NBLK;

    // ws: ebuf[E u2] | g1[16n fp16] | g2[8n fp16] | bh[NBLK*NBK] | tot | bs |
    //     dinv[n] | nrp[n+1] | W1h[8192 fp16]     (~37.7 MB at NBLK=1024)
    size_t off_ebuf = 0;
    size_t off_h1   = align64(off_ebuf + (size_t)E * 8);
    size_t off_h2   = align64(off_h1 + (size_t)16 * n * 2);
    size_t off_bh   = align64(off_h2 + (size_t)8 * n * 2);
    size_t off_tot  = align64(off_bh + (size_t)NBLK * NBK * 4);
    size_t off_bs   = align64(off_tot + (size_t)NBK * 4);
    size_t off_dinv = align64(off_bs + (size_t)(NBK + 1) * 4);
    size_t off_nrp  = align64(off_dinv + (size_t)n * 4);
    size_t off_w1h  = align64(off_nrp + (size_t)(n + 1) * 4);
    size_t need     = off_w1h + (size_t)512 * 16 * 2;

    if (ws_size >= need && NBK <= MAX_NBK && n <= (1 << 20)) {
        char* ws = (char*)d_ws;
        uint2*    ebuf = (uint2*)(ws + off_ebuf);
        __half*   g1   = (__half*)(ws + off_h1);
        __half*   g2   = (__half*)(ws + off_h2);
        int*      bh   = (int*)(ws + off_bh);
        int*      tot  = (int*)(ws + off_tot);
        int*      bs   = (int*)(ws + off_bs);
        float*    dinv = (float*)(ws + off_dinv);
        int*      nrp  = (int*)(ws + off_nrp);
        _Float16* w1h  = (_Float16*)(ws + off_w1h);

        k_prepW<<<32, B, 0, stream>>>(W1, w1h);
        k_hist<<<NBLK, B, 0, stream>>>(dst, bh, NBK, E, chunk);
        k_colscan<<<(NBK + 15) / 16, B, 0, stream>>>(bh, tot, NBK);
        k_scan_totals<<<1, B, 0, stream>>>(tot, bs, NBK, E);
        k_bin<<<NBLK, B, 0, stream>>>(src, dst, ew, bh, bs, ebuf, NBK, E, chunk);
        k_sortdeg<<<NBK, B, 0, stream>>>(ebuf, bs, nrp, dinv, n, NBK, E);

        k_gemm1<<<(n + 63) / 64, B, 0, stream>>>(x, w1h, dinv, g1, n);
        k_agg16g2<<<NB32, B, 0, stream>>>(nrp, ebuf, bs, dinv, g1, W2, b1, g2, n);
        k_agg8lsm<<<NB32, B, 0, stream>>>(nrp, ebuf, bs, dinv, g2, b2, out, n);
    } else {
        // fallback: atomic-scatter path (33n floats), fp32 everywhere
        float* deg  = (float*)d_ws;
        float* h1   = deg + n;
        float* h2   = h1;
        float* agg1 = h1 + (size_t)16 * n;
        int gn = (n + B - 1) / B, gE = (E + B - 1) / B;

        k_init_deg<<<gn, B, 0, stream>>>(deg, n);
        k_deg_scatter<<<gE, B, 0, stream>>>(dst, ew, deg, E);
        k_rsqrt_inplace<<<gn, B, 0, stream>>>(deg, n);
        k_gemm1f<<<(n + 15) / 16, B, 0, stream>>>(x, W1, h1, n);
        k_self_init<16><<<((size_t)16 * n + B - 1) / B, B, 0, stream>>>(deg, h1, agg1, n);
        k_scatter<16><<<((size_t)16 * E + B - 1) / B, B, 0, stream>>>(src, dst, ew, deg, h1, agg1, E);
        k_gemm2<<<((size_t)8 * n + B - 1) / B, B, 0, stream>>>(agg1, b1, W2, h2, n);
        k_self_init<8><<<((size_t)8 * n + B - 1) / B, B, 0, stream>>>(deg, h2, out, n);
        k_scatter<8><<<((size_t)8 * E + B - 1) / B, B, 0, stream>>>(src, dst, ew, deg, h2, out, E);
        k_logsoftmax<<<gn, B, 0, stream>>>(out, b2, n);
    }
}